// Round 1
// baseline (434.701 us; speedup 1.0000x reference)
//
#include <hip/hip_runtime.h>
#include <stdint.h>

#define N_NODES 50000
#define N_EDGES 800000
#define FEAT    128
#define NGRAPH  64

#define XB_BLKS   6250   // x cvt: 1.6M float4 / 256
#define W_BLKS    32     // two 128x128 weight cvts
#define E_BLKS    3125   // 800000 edges / 256
#define PREP_BLKS (XB_BLKS + W_BLKS + E_BLKS)
#define GEMM_BLKS 6250   // (N/16) m-tiles * 8 n-tiles / 4 waves

typedef __attribute__((ext_vector_type(8))) short short8;
typedef __attribute__((ext_vector_type(4))) float floatx4;

static __device__ __forceinline__ ushort f2bf(float f) {
  uint32_t x = __float_as_uint(f);
  x += 0x7FFF + ((x >> 16) & 1);   // RNE
  return (ushort)(x >> 16);
}
static __device__ __forceinline__ float bfLo(uint32_t u) {
  return __uint_as_float(u << 16);
}
static __device__ __forceinline__ float bfHi(uint32_t u) {
  return __uint_as_float(u & 0xFFFF0000u);
}

static __device__ __forceinline__ void cvt4(const float* __restrict__ in,
                                            ushort* __restrict__ out, int i) {
  float4 v = ((const float4*)in)[i];
  ushort4 u;
  u.x = f2bf(v.x); u.y = f2bf(v.y); u.z = f2bf(v.z); u.w = f2bf(v.w);
  ((ushort4*)out)[i] = u;
}

// ---- fused prep: cvt x, cvt w1/w2, count_deg (independent) --------------
// (coefT machinery removed: dinv is folded into GEMM/agg epilogues)
__global__ __launch_bounds__(256) void prep_fused(const float* __restrict__ x,
                                                  ushort* __restrict__ xb,
                                                  const float* __restrict__ w0,
                                                  const float* __restrict__ w1,
                                                  ushort* __restrict__ wb,
                                                  const int* __restrict__ dst,
                                                  int* __restrict__ cnt) {
  int b = blockIdx.x, t = threadIdx.x;
  if (b < XB_BLKS) {
    cvt4(x, xb, b * 256 + t);
  } else if (b < XB_BLKS + W_BLKS) {
    int i = (b - XB_BLKS) * 256 + t;           // 0..8191 over two weights
    if (i < 4096) cvt4(w0, wb, i);
    else cvt4(w1, wb + FEAT * FEAT, i - 4096);
  } else {
    int e = (b - XB_BLKS - W_BLKS) * 256 + t;
    if (e < N_EDGES) atomicAdd(&cnt[dst[e]], 1);
  }
}

// ---- fused: dinv + graph counts + scan1 (all read cnt) ------------------
__global__ __launch_bounds__(256) void dinv_scan1(const int* __restrict__ cnt,
                                                  const int* __restrict__ batch,
                                                  float* __restrict__ dinv,
                                                  float* __restrict__ cnt_g,
                                                  int* __restrict__ ptr,
                                                  int* __restrict__ bsums) {
  __shared__ int tmp[256];
  __shared__ int bins[NGRAPH];
  if (threadIdx.x < NGRAPH) bins[threadIdx.x] = 0;
  int i = blockIdx.x * 256 + threadIdx.x;
  int v = (i < N_NODES) ? cnt[i] : 0;
  tmp[threadIdx.x] = v;
  __syncthreads();
  for (int off = 1; off < 256; off <<= 1) {
    int t = (threadIdx.x >= off) ? tmp[threadIdx.x - off] : 0;
    __syncthreads();
    tmp[threadIdx.x] += t;
    __syncthreads();
  }
  if (i < N_NODES) ptr[i] = tmp[threadIdx.x] - v;           // exclusive
  if (threadIdx.x == 255) bsums[blockIdx.x] = tmp[255];
  if (i < N_NODES) {
    dinv[i] = rsqrtf((float)v + 1.0f);
    atomicAdd(&bins[batch[i]], 1);
  }
  __syncthreads();
  if (threadIdx.x < NGRAPH && bins[threadIdx.x] > 0)
    atomicAdd(&cnt_g[threadIdx.x], (float)bins[threadIdx.x]);
}

__global__ __launch_bounds__(256) void scan2(int* __restrict__ bsums, int nb) {
  __shared__ int tmp[256];
  int v = (threadIdx.x < nb) ? bsums[threadIdx.x] : 0;
  tmp[threadIdx.x] = v;
  __syncthreads();
  for (int off = 1; off < 256; off <<= 1) {
    int t = (threadIdx.x >= off) ? tmp[threadIdx.x - off] : 0;
    __syncthreads();
    tmp[threadIdx.x] += t;
    __syncthreads();
  }
  if (threadIdx.x < nb) bsums[threadIdx.x] = tmp[threadIdx.x] - v;  // exclusive
}

__global__ __launch_bounds__(256) void scan3(int* __restrict__ ptr,
                                             int* __restrict__ cursor,
                                             const int* __restrict__ bsums) {
  int i = blockIdx.x * 256 + threadIdx.x;
  if (i < N_NODES) {
    int p = ptr[i] + bsums[blockIdx.x];
    ptr[i] = p;
    cursor[i] = p;
  }
}

// ---- shared gemm body: [M,128] x [128,128] MFMA bf16, bf16 out ----------
// Epilogue scales row m by dinv[m]: output is the dinv_s-prescaled message.
static __device__ __forceinline__ void gemm_body(int wave, int lane,
                                                 const ushort* __restrict__ X,
                                                 const ushort* __restrict__ W,
                                                 ushort* __restrict__ XW,
                                                 const float* __restrict__ dinv) {
  int mt = wave >> 3;  // 8 n-tiles per m-tile
  int nt = wave & 7;
  if (mt >= N_NODES / 16) return;
  int m0 = mt * 16, n0 = nt * 16;
  int r = lane & 15, quad = lane >> 4;
  floatx4 acc = {0.f, 0.f, 0.f, 0.f};
  const ushort* xrow = X + (size_t)(m0 + r) * FEAT;
#pragma unroll
  for (int kb = 0; kb < 4; ++kb) {
    int k0 = kb * 32 + quad * 8;
    short8 a = *(const short8*)(xrow + k0);
    short8 b;
#pragma unroll
    for (int j = 0; j < 8; ++j) b[j] = (short)W[(size_t)(k0 + j) * FEAT + n0 + r];
    acc = __builtin_amdgcn_mfma_f32_16x16x32_bf16(a, b, acc, 0, 0, 0);
  }
#pragma unroll
  for (int reg = 0; reg < 4; ++reg) {
    int row = quad * 4 + reg;
    float di = dinv[m0 + row];
    XW[(size_t)(m0 + row) * FEAT + n0 + r] = f2bf(acc[reg] * di);
  }
}

__global__ __launch_bounds__(256) void gemm128(const ushort* __restrict__ X,
                                               const ushort* __restrict__ W,
                                               ushort* __restrict__ XW,
                                               const float* __restrict__ dinv) {
  gemm_body((blockIdx.x * 256 + threadIdx.x) >> 6, threadIdx.x & 63, X, W, XW, dinv);
}

// ---- fused: conv1 gemm (MFMA-bound) + fill_csr (scatter-bound) ----------
// fill is now 2 random transactions/edge: cursor atomic + 4B src store.
__global__ __launch_bounds__(256) void fill_gemm1(const ushort* __restrict__ X,
                                                  const ushort* __restrict__ W,
                                                  ushort* __restrict__ XW,
                                                  const float* __restrict__ dinv,
                                                  const int* __restrict__ src,
                                                  const int* __restrict__ dst,
                                                  int* __restrict__ cursor,
                                                  int* __restrict__ esrc) {
  if (blockIdx.x < GEMM_BLKS) {
    gemm_body((blockIdx.x * 256 + threadIdx.x) >> 6, threadIdx.x & 63, X, W, XW, dinv);
  } else {
    int e = (blockIdx.x - GEMM_BLKS) * 256 + threadIdx.x;
    if (e >= N_EDGES) return;
    int s = src[e];
    int d = dst[e];
    int pos = atomicAdd(&cursor[d], 1);
    esrc[pos] = s;
  }
}

// ---------------- aggregation: wave/node, 8-edge ILP ---------------------
// msg rows are pre-scaled by dinv[src]; epilogue applies dinv[dst].
// MODE 0: out bf16 = relu(di*sum + b)            (conv1 -> h1)
// MODE 1: out bf16 = di*relu(di*sum + b)         (conv2 -> g2, pre-scaled)
// MODE 2: out fp32 = di*sum                      (conv3 pre-pool, no bias)
template <int MODE>
__global__ __launch_bounds__(256) void agg_kernel(const ushort* __restrict__ msg,
                                                  const float* __restrict__ dinv,
                                                  const int* __restrict__ ptr,
                                                  const int* __restrict__ cnt,
                                                  const int* __restrict__ esrc,
                                                  const float* __restrict__ bias,
                                                  void* __restrict__ outp) {
  int wave = (blockIdx.x * 256 + threadIdx.x) >> 6;
  int lane = threadIdx.x & 63;
  if (wave >= N_NODES) return;
  int v = wave;
  float di = dinv[v];
  const uint32_t* m32 = (const uint32_t*)msg;   // 64 dwords per node row
  uint32_t su = m32[(size_t)v * 64 + lane];     // self term (weight 1)
  float ax0 = bfLo(su), ay0 = bfHi(su);
  float ax1 = 0.f, ay1 = 0.f, ax2 = 0.f, ay2 = 0.f, ax3 = 0.f, ay3 = 0.f;
  int start = ptr[v];
  int n = cnt[v];
  int i = 0;
  int pre = (4 - (start & 3)) & 3;              // align to int4 boundary
  if (pre > n) pre = n;
  for (; i < pre; ++i) {
    uint32_t u = m32[(size_t)esrc[start + i] * 64 + lane];
    ax0 += bfLo(u); ay0 += bfHi(u);
  }
  for (; i + 8 <= n; i += 8) {
    const int4* ep = (const int4*)(esrc + start + i);   // 16B-aligned
    int4 q0 = ep[0], q1 = ep[1];
    uint32_t u0 = m32[(size_t)q0.x * 64 + lane];
    uint32_t u1 = m32[(size_t)q0.y * 64 + lane];
    uint32_t u2 = m32[(size_t)q0.z * 64 + lane];
    uint32_t u3 = m32[(size_t)q0.w * 64 + lane];
    uint32_t u4 = m32[(size_t)q1.x * 64 + lane];
    uint32_t u5 = m32[(size_t)q1.y * 64 + lane];
    uint32_t u6 = m32[(size_t)q1.z * 64 + lane];
    uint32_t u7 = m32[(size_t)q1.w * 64 + lane];
    ax0 += bfLo(u0); ay0 += bfHi(u0);
    ax1 += bfLo(u1); ay1 += bfHi(u1);
    ax2 += bfLo(u2); ay2 += bfHi(u2);
    ax3 += bfLo(u3); ay3 += bfHi(u3);
    ax0 += bfLo(u4); ay0 += bfHi(u4);
    ax1 += bfLo(u5); ay1 += bfHi(u5);
    ax2 += bfLo(u6); ay2 += bfHi(u6);
    ax3 += bfLo(u7); ay3 += bfHi(u7);
  }
  for (; i < n; ++i) {
    uint32_t u = m32[(size_t)esrc[start + i] * 64 + lane];
    ax0 += bfLo(u); ay0 += bfHi(u);
  }
  float ax = (ax0 + ax1) + (ax2 + ax3);
  float ay = (ay0 + ay1) + (ay2 + ay3);
  if (MODE == 2) {
    ((float2*)outp)[(size_t)v * 64 + lane] = make_float2(ax * di, ay * di);
  } else {
    ax = fmaf(ax, di, bias[2 * lane]);
    ay = fmaf(ay, di, bias[2 * lane + 1]);
    ax = fmaxf(ax, 0.f);
    ay = fmaxf(ay, 0.f);
    if (MODE == 1) { ax *= di; ay *= di; }
    ushort2 h2;
    h2.x = f2bf(ax);
    h2.y = f2bf(ay);
    ((ushort2*)outp)[(size_t)v * 64 + lane] = h2;
  }
}

// ---------------- pool: segment-sum a3 over batch-sorted nodes -----------
// wave handles 16 consecutive nodes; flush atomics only at graph boundary.
__global__ __launch_bounds__(256) void pool_sum(const float* __restrict__ a3,
                                                const int* __restrict__ batch,
                                                float* __restrict__ P) {
  int wave = blockIdx.x * 4 + (threadIdx.x >> 6);
  int lane = threadIdx.x & 63;
  int v0 = wave * 16;
  if (v0 >= N_NODES) return;
  int vend = v0 + 16;
  if (vend > N_NODES) vend = N_NODES;
  const float2* a2 = (const float2*)a3;
  float ax = 0.f, ay = 0.f;
  int g = batch[v0];
  for (int v = v0; v < vend; ++v) {
    int gv = batch[v];
    if (gv != g) {
      atomicAdd(&P[(size_t)g * FEAT + 2 * lane], ax);
      atomicAdd(&P[(size_t)g * FEAT + 2 * lane + 1], ay);
      ax = 0.f; ay = 0.f; g = gv;
    }
    float2 t = a2[(size_t)v * 64 + lane];
    ax += t.x;
    ay += t.y;
  }
  atomicAdd(&P[(size_t)g * FEAT + 2 * lane], ax);
  atomicAdd(&P[(size_t)g * FEAT + 2 * lane + 1], ay);
}

// ---------------- fused head: Pn = P/cnt; f = Pn*W3+b3; fc1..fc5 ---------
__device__ __forceinline__ void head_layer(const float* __restrict__ IN,
                                           float* __restrict__ OUT,
                                           const float* __restrict__ w,
                                           const float* __restrict__ b,
                                           int K, int C, int Cp, int relu,
                                           float* __restrict__ gout, int t) {
  int parts = 1024 / Cp;
  int part = t / Cp;
  int c = t - part * Cp;
  int kchunk = K / parts;
  if (t < C) OUT[t] = b[t];
  __syncthreads();
  if (c < C) {
    int k0 = part * kchunk;
    float a0 = 0.f, a1 = 0.f, a2 = 0.f, a3 = 0.f;
    const float* wp = w + (size_t)k0 * C + c;
    if ((kchunk & 3) == 0) {
#pragma unroll 4
      for (int k = 0; k < kchunk; k += 4) {
        a0 = fmaf(IN[k0 + k],     wp[(size_t)k * C],       a0);
        a1 = fmaf(IN[k0 + k + 1], wp[(size_t)(k + 1) * C], a1);
        a2 = fmaf(IN[k0 + k + 2], wp[(size_t)(k + 2) * C], a2);
        a3 = fmaf(IN[k0 + k + 3], wp[(size_t)(k + 3) * C], a3);
      }
    } else {
      for (int k = 0; k < kchunk; ++k)
        a0 = fmaf(IN[k0 + k], wp[(size_t)k * C], a0);
    }
    atomicAdd(&OUT[c], (a0 + a1) + (a2 + a3));
  }
  __syncthreads();
  if (t < C) {
    float v = OUT[t];
    if (relu) { v = fmaxf(v, 0.f); OUT[t] = v; }
    if (gout) gout[t] = v;
  }
  __syncthreads();
}

__global__ __launch_bounds__(1024) void fc_head(const float* __restrict__ P,
                                                const float* __restrict__ cnt_g,
                                                const float* __restrict__ w3,
                                                const float* __restrict__ b3,
                                                const float* __restrict__ w1,
                                                const float* __restrict__ b1,
                                                const float* __restrict__ w2,
                                                const float* __restrict__ b2,
                                                const float* __restrict__ wf3,
                                                const float* __restrict__ bf3,
                                                const float* __restrict__ w4,
                                                const float* __restrict__ b4,
                                                const float* __restrict__ w5,
                                                const float* __restrict__ b5,
                                                float* __restrict__ out_f,
                                                float* __restrict__ out_y) {
  __shared__ float A[1024];
  __shared__ float B[1024];
  int r = blockIdx.x, t = threadIdx.x;
  if (t < FEAT) A[t] = P[r * FEAT + t] / fmaxf(cnt_g[r], 1.0f);   // Pn
  __syncthreads();
  head_layer(A, B, w3, b3, 128, 128, 128, 0, out_f + (size_t)r * FEAT, t);
  head_layer(B, A, w1, b1, 128, 1024, 1024, 1, nullptr, t);
  head_layer(A, B, w2, b2, 1024, 512, 512, 1, nullptr, t);
  head_layer(B, A, wf3, bf3, 512, 256, 256, 1, nullptr, t);
  head_layer(A, B, w4, b4, 256, 128, 128, 1, nullptr, t);
  head_layer(B, A, w5, b5, 128, 10, 16, 0, out_y + (size_t)r * 10, t);
}

// =========================================================================
extern "C" void kernel_launch(void* const* d_in, const int* in_sizes, int n_in,
                              void* d_out, int out_size, void* d_ws, size_t ws_size,
                              hipStream_t stream) {
  const float* x         = (const float*)d_in[0];
  const int*   ei        = (const int*)d_in[1];     // [2][E]: row0 src, row1 dst
  const int*   batch     = (const int*)d_in[2];
  const float* conv_w[3] = {(const float*)d_in[3], (const float*)d_in[5], (const float*)d_in[7]};
  const float* conv_b[3] = {(const float*)d_in[4], (const float*)d_in[6], (const float*)d_in[8]};
  const float* fc_w[5]   = {(const float*)d_in[9],  (const float*)d_in[11],
                            (const float*)d_in[13], (const float*)d_in[15],
                            (const float*)d_in[17]};
  const float* fc_b[5]   = {(const float*)d_in[10], (const float*)d_in[12],
                            (const float*)d_in[14], (const float*)d_in[16],
                            (const float*)d_in[18]};
  const int* e_src = ei;
  const int* e_dst = ei + N_EDGES;
  float* out_f = (float*)d_out;                  // [64][128] fp32  (output 0)
  float* out_y = (float*)d_out + NGRAPH * FEAT;  // [64][10]  fp32  (output 1)

  char* p = (char*)d_ws;
  auto carve = [&](size_t bytes) {
    char* r = p;
    p += (bytes + 255) & ~(size_t)255;
    return r;
  };
  int*    cnt_i   = (int*)carve(N_NODES * 4);
  float*  dinv    = (float*)carve(N_NODES * 4);
  int*    csr_ptr = (int*)carve(N_NODES * 4);
  int*    cursor  = (int*)carve(N_NODES * 4);
  int*    bsums   = (int*)carve(256 * 4);
  int*    esrc    = (int*)carve((size_t)N_EDGES * 4);             // CSR src only
  ushort* xb      = (ushort*)carve((size_t)N_NODES * FEAT * 2);   // bf16 x
  ushort* wb      = (ushort*)carve((size_t)2 * FEAT * FEAT * 2);  // bf16 conv1/2 W
  ushort* msl     = (ushort*)carve((size_t)N_NODES * FEAT * 2);   // bf16 messages
  ushort* hbuf    = (ushort*)carve((size_t)N_NODES * FEAT * 2);   // bf16 h
  float*  f_sum   = (float*)carve(NGRAPH * FEAT * 4);             // P
  float*  cnt_g   = (float*)carve(NGRAPH * 4);                    // adjacent to f_sum
  // a3 (fp32 [N][128], 25.6 MB) aliases xb+wb+msl (25.73 MB), all of which
  // are dead before agg<2> writes it (xb after fill_gemm1, wb after conv2
  // gemm, msl after agg<1> reads it).
  float* a3 = (float*)xb;

  const int BLK_N = (N_NODES + 255) / 256;   // 196

  // zero-init (ws + out are poisoned 0xAA each timed call)
  hipMemsetAsync(cnt_i, 0, N_NODES * 4, stream);
  hipMemsetAsync(f_sum, 0, NGRAPH * FEAT * 4 + 256, stream);      // f_sum + cnt_g

  // ---- fused prep: cvt x/w1/w2 + count_deg (1 dispatch) ----
  prep_fused<<<PREP_BLKS, 256, 0, stream>>>(x, xb, conv_w[0], conv_w[1], wb,
                                            e_dst, cnt_i);

  // ---- dinv + graph counts + scan1 (1 dispatch) ----
  dinv_scan1<<<BLK_N, 256, 0, stream>>>(cnt_i, batch, dinv, cnt_g, csr_ptr, bsums);
  scan2<<<1, 256, 0, stream>>>(bsums, BLK_N);
  scan3<<<BLK_N, 256, 0, stream>>>(csr_ptr, cursor, bsums);

  // ---- conv1 gemm (dinv-scaled msg) co-scheduled with fill_csr ----
  fill_gemm1<<<GEMM_BLKS + E_BLKS, 256, 0, stream>>>(
      xb, wb, msl, dinv, e_src, e_dst, cursor, esrc);

  const int AGG_BLKS  = (N_NODES + 3) / 4;
  const int POOL_BLKS = (N_NODES / 16 + 3) / 4 + 1;   // 782

  // ---- conv1 agg: h1 = relu(di*sum + b1) ----
  agg_kernel<0><<<AGG_BLKS, 256, 0, stream>>>(msl, dinv, csr_ptr, cnt_i, esrc,
                                              conv_b[0], hbuf);
  // ---- conv2: msg2 = di*(h1 W2); g2 = di*relu(di*sum + b2) ----
  gemm128<<<GEMM_BLKS, 256, 0, stream>>>(hbuf, wb + FEAT * FEAT, msl, dinv);
  agg_kernel<1><<<AGG_BLKS, 256, 0, stream>>>(msl, dinv, csr_ptr, cnt_i, esrc,
                                              conv_b[1], hbuf);
  // ---- conv3 pre-pool: a3 = di*(g2_self + sum g2_in), fp32 ----
  agg_kernel<2><<<AGG_BLKS, 256, 0, stream>>>(hbuf, dinv, csr_ptr, cnt_i, esrc,
                                              nullptr, a3);
  // ---- per-graph segment sum (batch sorted) ----
  pool_sum<<<POOL_BLKS, 256, 0, stream>>>(a3, batch, f_sum);

  // ---- fused head: Pn -> W3 -> fc1..fc5 (one launch) ----
  fc_head<<<NGRAPH, 1024, 0, stream>>>(f_sum, cnt_g, conv_w[2], conv_b[2],
                                       fc_w[0], fc_b[0], fc_w[1], fc_b[1],
                                       fc_w[2], fc_b[2], fc_w[3], fc_b[3],
                                       fc_w[4], fc_b[4], out_f, out_y);
}

// Round 2
// 396.870 us; speedup vs baseline: 1.0953x; 1.0953x over previous
//
#include <hip/hip_runtime.h>
#include <stdint.h>

#define N_NODES 50000
#define N_EDGES 800000
#define FEAT    128
#define NGRAPH  64

#define XB_BLKS   6250   // x cvt: 1.6M float4 / 256
#define W_BLKS    32     // two 128x128 weight cvts (transposed)
#define E_BLKS    3125   // 800000 edges / 256
#define PREP_BLKS (XB_BLKS + W_BLKS + E_BLKS)
#define GEMM_BLKS 6250   // (N/16) m-tiles * 8 n-tiles / 4 waves

typedef __attribute__((ext_vector_type(8))) short short8;
typedef __attribute__((ext_vector_type(4))) float floatx4;

static __device__ __forceinline__ ushort f2bf(float f) {
  uint32_t x = __float_as_uint(f);
  x += 0x7FFF + ((x >> 16) & 1);   // RNE
  return (ushort)(x >> 16);
}
static __device__ __forceinline__ float bfLo(uint32_t u) {
  return __uint_as_float(u << 16);
}
static __device__ __forceinline__ float bfHi(uint32_t u) {
  return __uint_as_float(u & 0xFFFF0000u);
}

static __device__ __forceinline__ void cvt4(const float* __restrict__ in,
                                            ushort* __restrict__ out, int i) {
  float4 v = ((const float4*)in)[i];
  ushort4 u;
  u.x = f2bf(v.x); u.y = f2bf(v.y); u.z = f2bf(v.z); u.w = f2bf(v.w);
  ((ushort4*)out)[i] = u;
}

// cvt + transpose: in is row-major [128][128] fp32, out is [n][k] bf16
static __device__ __forceinline__ void cvt4T(const float* __restrict__ in,
                                             ushort* __restrict__ outT, int i) {
  float4 v = ((const float4*)in)[i];
  int k = (4 * i) >> 7;          // row
  int n = (4 * i) & 127;         // col
  outT[(size_t)(n + 0) * FEAT + k] = f2bf(v.x);
  outT[(size_t)(n + 1) * FEAT + k] = f2bf(v.y);
  outT[(size_t)(n + 2) * FEAT + k] = f2bf(v.z);
  outT[(size_t)(n + 3) * FEAT + k] = f2bf(v.w);
}

// ---- fused prep: cvt x, cvt+transpose w1/w2, count_deg + rank -----------
// rank[e] = this edge's ordinal among edges sharing its dst; the ONLY
// atomic pass over edges (fill becomes deterministic).
__global__ __launch_bounds__(256) void prep_fused(const float* __restrict__ x,
                                                  ushort* __restrict__ xb,
                                                  const float* __restrict__ w0,
                                                  const float* __restrict__ w1,
                                                  ushort* __restrict__ wbT,
                                                  const int* __restrict__ dst,
                                                  int* __restrict__ cnt,
                                                  int* __restrict__ rank) {
  int b = blockIdx.x, t = threadIdx.x;
  if (b < XB_BLKS) {
    cvt4(x, xb, b * 256 + t);
  } else if (b < XB_BLKS + W_BLKS) {
    int i = (b - XB_BLKS) * 256 + t;           // 0..8191 over two weights
    if (i < 4096) cvt4T(w0, wbT, i);
    else cvt4T(w1, wbT + FEAT * FEAT, i - 4096);
  } else {
    int e = (b - XB_BLKS - W_BLKS) * 256 + t;
    if (e < N_EDGES) rank[e] = atomicAdd(&cnt[dst[e]], 1);
  }
}

// ---- fused: dinv + graph counts + scan1 (all read cnt) ------------------
__global__ __launch_bounds__(256) void dinv_scan1(const int* __restrict__ cnt,
                                                  const int* __restrict__ batch,
                                                  float* __restrict__ dinv,
                                                  float* __restrict__ cnt_g,
                                                  int* __restrict__ ptr,
                                                  int* __restrict__ bsums) {
  __shared__ int tmp[256];
  __shared__ int bins[NGRAPH];
  if (threadIdx.x < NGRAPH) bins[threadIdx.x] = 0;
  int i = blockIdx.x * 256 + threadIdx.x;
  int v = (i < N_NODES) ? cnt[i] : 0;
  tmp[threadIdx.x] = v;
  __syncthreads();
  for (int off = 1; off < 256; off <<= 1) {
    int t = (threadIdx.x >= off) ? tmp[threadIdx.x - off] : 0;
    __syncthreads();
    tmp[threadIdx.x] += t;
    __syncthreads();
  }
  if (i < N_NODES) ptr[i] = tmp[threadIdx.x] - v;           // exclusive
  if (threadIdx.x == 255) bsums[blockIdx.x] = tmp[255];
  if (i < N_NODES) {
    dinv[i] = rsqrtf((float)v + 1.0f);
    atomicAdd(&bins[batch[i]], 1);
  }
  __syncthreads();
  if (threadIdx.x < NGRAPH && bins[threadIdx.x] > 0)
    atomicAdd(&cnt_g[threadIdx.x], (float)bins[threadIdx.x]);
}

__global__ __launch_bounds__(256) void scan2(int* __restrict__ bsums, int nb) {
  __shared__ int tmp[256];
  int v = (threadIdx.x < nb) ? bsums[threadIdx.x] : 0;
  tmp[threadIdx.x] = v;
  __syncthreads();
  for (int off = 1; off < 256; off <<= 1) {
    int t = (threadIdx.x >= off) ? tmp[threadIdx.x - off] : 0;
    __syncthreads();
    tmp[threadIdx.x] += t;
    __syncthreads();
  }
  if (threadIdx.x < nb) bsums[threadIdx.x] = tmp[threadIdx.x] - v;  // exclusive
}

__global__ __launch_bounds__(256) void scan3(int* __restrict__ ptr,
                                             const int* __restrict__ bsums) {
  int i = blockIdx.x * 256 + threadIdx.x;
  if (i < N_NODES) ptr[i] += bsums[blockIdx.x];
}

// ---- shared gemm body: [M,128] x [128,128]^T MFMA bf16, bf16 out --------
// W is stored transposed ([n][k]) so B fragments load as contiguous short8.
// Epilogue scales row m by dinv[m]: output is the dinv_s-prescaled message.
static __device__ __forceinline__ void gemm_body(int wave, int lane,
                                                 const ushort* __restrict__ X,
                                                 const ushort* __restrict__ WT,
                                                 ushort* __restrict__ XW,
                                                 const float* __restrict__ dinv) {
  int mt = wave >> 3;  // 8 n-tiles per m-tile
  int nt = wave & 7;
  if (mt >= N_NODES / 16) return;
  int m0 = mt * 16, n0 = nt * 16;
  int r = lane & 15, quad = lane >> 4;
  floatx4 acc = {0.f, 0.f, 0.f, 0.f};
  const ushort* xrow = X + (size_t)(m0 + r) * FEAT;
  const ushort* wrow = WT + (size_t)(n0 + r) * FEAT;
#pragma unroll
  for (int kb = 0; kb < 4; ++kb) {
    int k0 = kb * 32 + quad * 8;
    short8 a = *(const short8*)(xrow + k0);
    short8 b = *(const short8*)(wrow + k0);
    acc = __builtin_amdgcn_mfma_f32_16x16x32_bf16(a, b, acc, 0, 0, 0);
  }
#pragma unroll
  for (int reg = 0; reg < 4; ++reg) {
    int row = quad * 4 + reg;
    float di = dinv[m0 + row];
    XW[(size_t)(m0 + row) * FEAT + n0 + r] = f2bf(acc[reg] * di);
  }
}

__global__ __launch_bounds__(256) void gemm128(const ushort* __restrict__ X,
                                               const ushort* __restrict__ WT,
                                               ushort* __restrict__ XW,
                                               const float* __restrict__ dinv) {
  gemm_body((blockIdx.x * 256 + threadIdx.x) >> 6, threadIdx.x & 63, X, WT, XW, dinv);
}

// ---- fused: conv1 gemm (MFMA) + fill_csr (atomic-free streaming) --------
// fill: pos = csr_ptr[dst] + rank (both precomputed) -> one 4B scatter.
__global__ __launch_bounds__(256) void fill_gemm1(const ushort* __restrict__ X,
                                                  const ushort* __restrict__ WT,
                                                  ushort* __restrict__ XW,
                                                  const float* __restrict__ dinv,
                                                  const int* __restrict__ src,
                                                  const int* __restrict__ dst,
                                                  const int* __restrict__ ptr,
                                                  const int* __restrict__ rank,
                                                  int* __restrict__ esrc) {
  if (blockIdx.x < GEMM_BLKS) {
    gemm_body((blockIdx.x * 256 + threadIdx.x) >> 6, threadIdx.x & 63, X, WT, XW, dinv);
  } else {
    int e = (blockIdx.x - GEMM_BLKS) * 256 + threadIdx.x;
    if (e >= N_EDGES) return;
    esrc[ptr[dst[e]] + rank[e]] = src[e];
  }
}

// ---------------- aggregation: wave/node, 8-edge ILP ---------------------
// msg rows are pre-scaled by dinv[src]; epilogue applies dinv[dst].
// MODE 0: out bf16 = relu(di*sum + b)            (conv1 -> h1)
// MODE 1: out bf16 = di*relu(di*sum + b)         (conv2 -> g2, pre-scaled)
// MODE 2: out fp32 = di*sum                      (conv3 pre-pool, no bias)
template <int MODE>
__global__ __launch_bounds__(256) void agg_kernel(const ushort* __restrict__ msg,
                                                  const float* __restrict__ dinv,
                                                  const int* __restrict__ ptr,
                                                  const int* __restrict__ cnt,
                                                  const int* __restrict__ esrc,
                                                  const float* __restrict__ bias,
                                                  void* __restrict__ outp) {
  int wave = (blockIdx.x * 256 + threadIdx.x) >> 6;
  int lane = threadIdx.x & 63;
  if (wave >= N_NODES) return;
  int v = wave;
  float di = dinv[v];
  const uint32_t* m32 = (const uint32_t*)msg;   // 64 dwords per node row
  uint32_t su = m32[(size_t)v * 64 + lane];     // self term (weight 1)
  float ax0 = bfLo(su), ay0 = bfHi(su);
  float ax1 = 0.f, ay1 = 0.f, ax2 = 0.f, ay2 = 0.f, ax3 = 0.f, ay3 = 0.f;
  int start = ptr[v];
  int n = cnt[v];
  int i = 0;
  int pre = (4 - (start & 3)) & 3;              // align to int4 boundary
  if (pre > n) pre = n;
  for (; i < pre; ++i) {
    uint32_t u = m32[(size_t)esrc[start + i] * 64 + lane];
    ax0 += bfLo(u); ay0 += bfHi(u);
  }
  for (; i + 8 <= n; i += 8) {
    const int4* ep = (const int4*)(esrc + start + i);   // 16B-aligned
    int4 q0 = ep[0], q1 = ep[1];
    uint32_t u0 = m32[(size_t)q0.x * 64 + lane];
    uint32_t u1 = m32[(size_t)q0.y * 64 + lane];
    uint32_t u2 = m32[(size_t)q0.z * 64 + lane];
    uint32_t u3 = m32[(size_t)q0.w * 64 + lane];
    uint32_t u4 = m32[(size_t)q1.x * 64 + lane];
    uint32_t u5 = m32[(size_t)q1.y * 64 + lane];
    uint32_t u6 = m32[(size_t)q1.z * 64 + lane];
    uint32_t u7 = m32[(size_t)q1.w * 64 + lane];
    ax0 += bfLo(u0); ay0 += bfHi(u0);
    ax1 += bfLo(u1); ay1 += bfHi(u1);
    ax2 += bfLo(u2); ay2 += bfHi(u2);
    ax3 += bfLo(u3); ay3 += bfHi(u3);
    ax0 += bfLo(u4); ay0 += bfHi(u4);
    ax1 += bfLo(u5); ay1 += bfHi(u5);
    ax2 += bfLo(u6); ay2 += bfHi(u6);
    ax3 += bfLo(u7); ay3 += bfHi(u7);
  }
  for (; i < n; ++i) {
    uint32_t u = m32[(size_t)esrc[start + i] * 64 + lane];
    ax0 += bfLo(u); ay0 += bfHi(u);
  }
  float ax = (ax0 + ax1) + (ax2 + ax3);
  float ay = (ay0 + ay1) + (ay2 + ay3);
  if (MODE == 2) {
    ((float2*)outp)[(size_t)v * 64 + lane] = make_float2(ax * di, ay * di);
  } else {
    ax = fmaf(ax, di, bias[2 * lane]);
    ay = fmaf(ay, di, bias[2 * lane + 1]);
    ax = fmaxf(ax, 0.f);
    ay = fmaxf(ay, 0.f);
    if (MODE == 1) { ax *= di; ay *= di; }
    ushort2 h2;
    h2.x = f2bf(ax);
    h2.y = f2bf(ay);
    ((ushort2*)outp)[(size_t)v * 64 + lane] = h2;
  }
}

// ---------------- pool: segment-sum a3 over batch-sorted nodes -----------
__global__ __launch_bounds__(256) void pool_sum(const float* __restrict__ a3,
                                                const int* __restrict__ batch,
                                                float* __restrict__ P) {
  int wave = blockIdx.x * 4 + (threadIdx.x >> 6);
  int lane = threadIdx.x & 63;
  int v0 = wave * 16;
  if (v0 >= N_NODES) return;
  int vend = v0 + 16;
  if (vend > N_NODES) vend = N_NODES;
  const float2* a2 = (const float2*)a3;
  float ax = 0.f, ay = 0.f;
  int g = batch[v0];
  for (int v = v0; v < vend; ++v) {
    int gv = batch[v];
    if (gv != g) {
      atomicAdd(&P[(size_t)g * FEAT + 2 * lane], ax);
      atomicAdd(&P[(size_t)g * FEAT + 2 * lane + 1], ay);
      ax = 0.f; ay = 0.f; g = gv;
    }
    float2 t = a2[(size_t)v * 64 + lane];
    ax += t.x;
    ay += t.y;
  }
  atomicAdd(&P[(size_t)g * FEAT + 2 * lane], ax);
  atomicAdd(&P[(size_t)g * FEAT + 2 * lane + 1], ay);
}

// ---------------- fused head: Pn = P/cnt; f = Pn*W3+b3; fc1..fc5 ---------
__device__ __forceinline__ void head_layer(const float* __restrict__ IN,
                                           float* __restrict__ OUT,
                                           const float* __restrict__ w,
                                           const float* __restrict__ b,
                                           int K, int C, int Cp, int relu,
                                           float* __restrict__ gout, int t) {
  int parts = 1024 / Cp;
  int part = t / Cp;
  int c = t - part * Cp;
  int kchunk = K / parts;
  if (t < C) OUT[t] = b[t];
  __syncthreads();
  if (c < C) {
    int k0 = part * kchunk;
    float a0 = 0.f, a1 = 0.f, a2 = 0.f, a3 = 0.f;
    const float* wp = w + (size_t)k0 * C + c;
    if ((kchunk & 3) == 0) {
#pragma unroll 4
      for (int k = 0; k < kchunk; k += 4) {
        a0 = fmaf(IN[k0 + k],     wp[(size_t)k * C],       a0);
        a1 = fmaf(IN[k0 + k + 1], wp[(size_t)(k + 1) * C], a1);
        a2 = fmaf(IN[k0 + k + 2], wp[(size_t)(k + 2) * C], a2);
        a3 = fmaf(IN[k0 + k + 3], wp[(size_t)(k + 3) * C], a3);
      }
    } else {
      for (int k = 0; k < kchunk; ++k)
        a0 = fmaf(IN[k0 + k], wp[(size_t)k * C], a0);
    }
    atomicAdd(&OUT[c], (a0 + a1) + (a2 + a3));
  }
  __syncthreads();
  if (t < C) {
    float v = OUT[t];
    if (relu) { v = fmaxf(v, 0.f); OUT[t] = v; }
    if (gout) gout[t] = v;
  }
  __syncthreads();
}

__global__ __launch_bounds__(1024) void fc_head(const float* __restrict__ P,
                                                const float* __restrict__ cnt_g,
                                                const float* __restrict__ w3,
                                                const float* __restrict__ b3,
                                                const float* __restrict__ w1,
                                                const float* __restrict__ b1,
                                                const float* __restrict__ w2,
                                                const float* __restrict__ b2,
                                                const float* __restrict__ wf3,
                                                const float* __restrict__ bf3,
                                                const float* __restrict__ w4,
                                                const float* __restrict__ b4,
                                                const float* __restrict__ w5,
                                                const float* __restrict__ b5,
                                                float* __restrict__ out_f,
                                                float* __restrict__ out_y) {
  __shared__ float A[1024];
  __shared__ float B[1024];
  int r = blockIdx.x, t = threadIdx.x;
  if (t < FEAT) A[t] = P[r * FEAT + t] / fmaxf(cnt_g[r], 1.0f);   // Pn
  __syncthreads();
  head_layer(A, B, w3, b3, 128, 128, 128, 0, out_f + (size_t)r * FEAT, t);
  head_layer(B, A, w1, b1, 128, 1024, 1024, 1, nullptr, t);
  head_layer(A, B, w2, b2, 1024, 512, 512, 1, nullptr, t);
  head_layer(B, A, wf3, bf3, 512, 256, 256, 1, nullptr, t);
  head_layer(A, B, w4, b4, 256, 128, 128, 1, nullptr, t);
  head_layer(B, A, w5, b5, 128, 10, 16, 0, out_y + (size_t)r * 10, t);
}

// =========================================================================
extern "C" void kernel_launch(void* const* d_in, const int* in_sizes, int n_in,
                              void* d_out, int out_size, void* d_ws, size_t ws_size,
                              hipStream_t stream) {
  const float* x         = (const float*)d_in[0];
  const int*   ei        = (const int*)d_in[1];     // [2][E]: row0 src, row1 dst
  const int*   batch     = (const int*)d_in[2];
  const float* conv_w[3] = {(const float*)d_in[3], (const float*)d_in[5], (const float*)d_in[7]};
  const float* conv_b[3] = {(const float*)d_in[4], (const float*)d_in[6], (const float*)d_in[8]};
  const float* fc_w[5]   = {(const float*)d_in[9],  (const float*)d_in[11],
                            (const float*)d_in[13], (const float*)d_in[15],
                            (const float*)d_in[17]};
  const float* fc_b[5]   = {(const float*)d_in[10], (const float*)d_in[12],
                            (const float*)d_in[14], (const float*)d_in[16],
                            (const float*)d_in[18]};
  const int* e_src = ei;
  const int* e_dst = ei + N_EDGES;
  float* out_f = (float*)d_out;                  // [64][128] fp32  (output 0)
  float* out_y = (float*)d_out + NGRAPH * FEAT;  // [64][10]  fp32  (output 1)

  char* p = (char*)d_ws;
  auto carve = [&](size_t bytes) {
    char* r = p;
    p += (bytes + 255) & ~(size_t)255;
    return r;
  };
  int*    cnt_i   = (int*)carve(N_NODES * 4);
  float*  dinv    = (float*)carve(N_NODES * 4);
  int*    csr_ptr = (int*)carve(N_NODES * 4);
  int*    bsums   = (int*)carve(256 * 4);
  int*    rank    = (int*)carve((size_t)N_EDGES * 4);             // edge rank in dst
  int*    esrc    = (int*)carve((size_t)N_EDGES * 4);             // CSR src only
  ushort* xb      = (ushort*)carve((size_t)N_NODES * FEAT * 2);   // bf16 x
  ushort* wbT     = (ushort*)carve((size_t)2 * FEAT * FEAT * 2);  // bf16 W^T conv1/2
  ushort* msl     = (ushort*)carve((size_t)N_NODES * FEAT * 2);   // bf16 messages
  ushort* hbuf    = (ushort*)carve((size_t)N_NODES * FEAT * 2);   // bf16 h
  float*  f_sum   = (float*)carve(NGRAPH * FEAT * 4);             // P
  float*  cnt_g   = (float*)carve(NGRAPH * 4);                    // adjacent to f_sum
  // a3 (fp32 [N][128], 25.6 MB) aliases xb+wbT+msl (25.73 MB), all of which
  // are dead before agg<2> writes it (xb after fill_gemm1, wbT after conv2
  // gemm, msl after agg<1> reads it).
  float* a3 = (float*)xb;

  const int BLK_N = (N_NODES + 255) / 256;   // 196

  // zero-init (ws + out are poisoned 0xAA each timed call)
  hipMemsetAsync(cnt_i, 0, N_NODES * 4, stream);
  hipMemsetAsync(f_sum, 0, NGRAPH * FEAT * 4 + 256, stream);      // f_sum + cnt_g

  // ---- fused prep: cvt x/w1T/w2T + count_deg + edge ranks (1 dispatch) --
  prep_fused<<<PREP_BLKS, 256, 0, stream>>>(x, xb, conv_w[0], conv_w[1], wbT,
                                            e_dst, cnt_i, rank);

  // ---- dinv + graph counts + scan1 (1 dispatch) ----
  dinv_scan1<<<BLK_N, 256, 0, stream>>>(cnt_i, batch, dinv, cnt_g, csr_ptr, bsums);
  scan2<<<1, 256, 0, stream>>>(bsums, BLK_N);
  scan3<<<BLK_N, 256, 0, stream>>>(csr_ptr, bsums);

  // ---- conv1 gemm (dinv-scaled msg) co-scheduled with atomic-free fill --
  fill_gemm1<<<GEMM_BLKS + E_BLKS, 256, 0, stream>>>(
      xb, wbT, msl, dinv, e_src, e_dst, csr_ptr, rank, esrc);

  const int AGG_BLKS  = (N_NODES + 3) / 4;
  const int POOL_BLKS = (N_NODES / 16 + 3) / 4 + 1;   // 782

  // ---- conv1 agg: h1 = relu(di*sum + b1) ----
  agg_kernel<0><<<AGG_BLKS, 256, 0, stream>>>(msl, dinv, csr_ptr, cnt_i, esrc,
                                              conv_b[0], hbuf);
  // ---- conv2: msg2 = di*(h1 W2); g2 = di*relu(di*sum + b2) ----
  gemm128<<<GEMM_BLKS, 256, 0, stream>>>(hbuf, wbT + FEAT * FEAT, msl, dinv);
  agg_kernel<1><<<AGG_BLKS, 256, 0, stream>>>(msl, dinv, csr_ptr, cnt_i, esrc,
                                              conv_b[1], hbuf);
  // ---- conv3 pre-pool: a3 = di*(g2_self + sum g2_in), fp32 ----
  agg_kernel<2><<<AGG_BLKS, 256, 0, stream>>>(hbuf, dinv, csr_ptr, cnt_i, esrc,
                                              nullptr, a3);
  // ---- per-graph segment sum (batch sorted) ----
  pool_sum<<<POOL_BLKS, 256, 0, stream>>>(a3, batch, f_sum);

  // ---- fused head: Pn -> W3 -> fc1..fc5 (one launch) ----
  fc_head<<<NGRAPH, 1024, 0, stream>>>(f_sum, cnt_g, conv_w[2], conv_b[2],
                                       fc_w[0], fc_b[0], fc_w[1], fc_b[1],
                                       fc_w[2], fc_b[2], fc_w[3], fc_b[3],
                                       fc_w[4], fc_b[4], out_f, out_y);
}

// Round 3
// 373.454 us; speedup vs baseline: 1.1640x; 1.0627x over previous
//
#include <hip/hip_runtime.h>
#include <stdint.h>

#define N_NODES 50000
#define N_EDGES 800000
#define FEAT    128
#define NGRAPH  64

#define E_BLKS    3125   // 800000 edges / 256
#define GEMM_BLKS 6250   // (N/16) m-tiles * 8 n-tiles / 4 waves
#define GR_BLKS   (GEMM_BLKS + E_BLKS)   // 9375, roles interleaved 2:1

typedef __attribute__((ext_vector_type(8))) short short8;
typedef __attribute__((ext_vector_type(4))) float floatx4;

static __device__ __forceinline__ ushort f2bf(float f) {
  uint32_t x = __float_as_uint(f);
  x += 0x7FFF + ((x >> 16) & 1);   // RNE
  return (ushort)(x >> 16);
}
static __device__ __forceinline__ float bfLo(uint32_t u) {
  return __uint_as_float(u << 16);
}
static __device__ __forceinline__ float bfHi(uint32_t u) {
  return __uint_as_float(u & 0xFFFF0000u);
}

// cvt + transpose: in is row-major [128][128] fp32 [k][n], out is [n][k] bf16
static __device__ __forceinline__ void cvt4T(const float* __restrict__ in,
                                             ushort* __restrict__ outT, int i) {
  float4 v = ((const float4*)in)[i];
  int k = (4 * i) >> 7;          // row
  int n = (4 * i) & 127;         // col
  outT[(size_t)(n + 0) * FEAT + k] = f2bf(v.x);
  outT[(size_t)(n + 1) * FEAT + k] = f2bf(v.y);
  outT[(size_t)(n + 2) * FEAT + k] = f2bf(v.z);
  outT[(size_t)(n + 3) * FEAT + k] = f2bf(v.w);
}

// ---- tiny: transpose-cvt both conv weights (runs before gemm_rank) ------
__global__ __launch_bounds__(256) void wcvt(const float* __restrict__ w0,
                                            const float* __restrict__ w1,
                                            ushort* __restrict__ wbT) {
  int i = blockIdx.x * 256 + threadIdx.x;   // 0..8191
  if (i < 4096) cvt4T(w0, wbT, i);
  else cvt4T(w1, wbT + FEAT * FEAT, i - 4096);
}

// ---- gemm body, A from fp32 (in-register cvt), B from bf16 W^T ----------
// No dinv in epilogue (dinv not available yet when co-run with atomics).
static __device__ __forceinline__ void gemm_body_f32a(int wave, int lane,
                                                      const float* __restrict__ X,
                                                      const ushort* __restrict__ WT,
                                                      ushort* __restrict__ XW) {
  int mt = wave >> 3;  // 8 n-tiles per m-tile
  int nt = wave & 7;
  int m0 = mt * 16, n0 = nt * 16;
  int r = lane & 15, quad = lane >> 4;
  floatx4 acc = {0.f, 0.f, 0.f, 0.f};
  const float* xrow = X + (size_t)(m0 + r) * FEAT;
  const ushort* wrow = WT + (size_t)(n0 + r) * FEAT;
#pragma unroll
  for (int kb = 0; kb < 4; ++kb) {
    int k0 = kb * 32 + quad * 8;
    float4 f0 = *(const float4*)(xrow + k0);
    float4 f1 = *(const float4*)(xrow + k0 + 4);
    short8 a;
    a[0] = (short)f2bf(f0.x); a[1] = (short)f2bf(f0.y);
    a[2] = (short)f2bf(f0.z); a[3] = (short)f2bf(f0.w);
    a[4] = (short)f2bf(f1.x); a[5] = (short)f2bf(f1.y);
    a[6] = (short)f2bf(f1.z); a[7] = (short)f2bf(f1.w);
    short8 b = *(const short8*)(wrow + k0);
    acc = __builtin_amdgcn_mfma_f32_16x16x32_bf16(a, b, acc, 0, 0, 0);
  }
#pragma unroll
  for (int reg = 0; reg < 4; ++reg) {
    int row = quad * 4 + reg;
    XW[(size_t)(m0 + row) * FEAT + n0 + r] = f2bf(acc[reg]);
  }
}

// ---- K1: conv1 gemm interleaved 2:1 with the rank-atomic pass -----------
// role = blockIdx%3: {0,1} -> gemm blocks (6250), {2} -> edge blocks (3125).
// Interleaving keeps MFMA/VMEM busy while fabric atomics drain.
__global__ __launch_bounds__(256) void gemm_rank(const float* __restrict__ x,
                                                 const ushort* __restrict__ wbT,
                                                 ushort* __restrict__ msl,
                                                 const int* __restrict__ dst,
                                                 int* __restrict__ cnt,
                                                 int* __restrict__ rank) {
  int b = blockIdx.x, t = threadIdx.x;
  int third = b / 3;
  int rem = b - third * 3;
  if (rem < 2) {
    int gb = third * 2 + rem;                  // 0..6249
    gemm_body_f32a(gb * 4 + (t >> 6), t & 63, x, wbT, msl);
  } else {
    int e = third * 256 + t;                   // 0..799999 exactly
    rank[e] = atomicAdd(&cnt[dst[e]], 1);
  }
}

// ---- fused: dinv + graph counts + scan1 (all read cnt) ------------------
__global__ __launch_bounds__(256) void dinv_scan1(const int* __restrict__ cnt,
                                                  const int* __restrict__ batch,
                                                  float* __restrict__ dinv,
                                                  float* __restrict__ cnt_g,
                                                  int* __restrict__ ptr,
                                                  int* __restrict__ bsums) {
  __shared__ int tmp[256];
  __shared__ int bins[NGRAPH];
  if (threadIdx.x < NGRAPH) bins[threadIdx.x] = 0;
  int i = blockIdx.x * 256 + threadIdx.x;
  int v = (i < N_NODES) ? cnt[i] : 0;
  tmp[threadIdx.x] = v;
  __syncthreads();
  for (int off = 1; off < 256; off <<= 1) {
    int t = (threadIdx.x >= off) ? tmp[threadIdx.x - off] : 0;
    __syncthreads();
    tmp[threadIdx.x] += t;
    __syncthreads();
  }
  if (i < N_NODES) ptr[i] = tmp[threadIdx.x] - v;           // exclusive
  if (threadIdx.x == 255) bsums[blockIdx.x] = tmp[255];
  if (i < N_NODES) {
    dinv[i] = rsqrtf((float)v + 1.0f);
    atomicAdd(&bins[batch[i]], 1);
  }
  __syncthreads();
  if (threadIdx.x < NGRAPH && bins[threadIdx.x] > 0)
    atomicAdd(&cnt_g[threadIdx.x], (float)bins[threadIdx.x]);
}

__global__ __launch_bounds__(256) void scan2(int* __restrict__ bsums, int nb) {
  __shared__ int tmp[256];
  int v = (threadIdx.x < nb) ? bsums[threadIdx.x] : 0;
  tmp[threadIdx.x] = v;
  __syncthreads();
  for (int off = 1; off < 256; off <<= 1) {
    int t = (threadIdx.x >= off) ? tmp[threadIdx.x - off] : 0;
    __syncthreads();
    tmp[threadIdx.x] += t;
    __syncthreads();
  }
  if (threadIdx.x < nb) bsums[threadIdx.x] = tmp[threadIdx.x] - v;  // exclusive
}

__global__ __launch_bounds__(256) void scan3(int* __restrict__ ptr,
                                             const int* __restrict__ bsums) {
  int i = blockIdx.x * 256 + threadIdx.x;
  if (i < N_NODES) ptr[i] += bsums[blockIdx.x];
}

// ---- fill: atomic-free CSR scatter, payload {src, dinv[src]} ------------
__global__ __launch_bounds__(256) void fill_csr(const int* __restrict__ src,
                                                const int* __restrict__ dst,
                                                const int* __restrict__ rank,
                                                const int* __restrict__ ptr,
                                                const float* __restrict__ dinv,
                                                int2* __restrict__ edges) {
  int e = blockIdx.x * 256 + threadIdx.x;
  if (e >= N_EDGES) return;
  int s = src[e];
  edges[ptr[dst[e]] + rank[e]] = make_int2(s, __float_as_int(dinv[s]));
}

// ---- conv2 gemm: bf16 A x bf16 W^T, no dinv epilogue --------------------
__global__ __launch_bounds__(256) void gemm128(const ushort* __restrict__ X,
                                               const ushort* __restrict__ WT,
                                               ushort* __restrict__ XW) {
  int wave = (blockIdx.x * 256 + threadIdx.x) >> 6;
  int lane = threadIdx.x & 63;
  int mt = wave >> 3;
  int nt = wave & 7;
  int m0 = mt * 16, n0 = nt * 16;
  int r = lane & 15, quad = lane >> 4;
  floatx4 acc = {0.f, 0.f, 0.f, 0.f};
  const ushort* xrow = X + (size_t)(m0 + r) * FEAT;
  const ushort* wrow = WT + (size_t)(n0 + r) * FEAT;
#pragma unroll
  for (int kb = 0; kb < 4; ++kb) {
    int k0 = kb * 32 + quad * 8;
    short8 a = *(const short8*)(xrow + k0);
    short8 b = *(const short8*)(wrow + k0);
    acc = __builtin_amdgcn_mfma_f32_16x16x32_bf16(a, b, acc, 0, 0, 0);
  }
#pragma unroll
  for (int reg = 0; reg < 4; ++reg) {
    int row = quad * 4 + reg;
    XW[(size_t)(m0 + row) * FEAT + n0 + r] = f2bf(acc[reg]);
  }
}

// ---------------- aggregation: wave/node, 8-edge ILP, per-edge dinv_s ----
// out = di * (sum_e dinv_s*msg[s] + di*msg[v]) [+ b, relu]
// MODE 0: out bf16 = relu(di*acc + b)   (conv1/conv2)
// MODE 2: out fp32 = di*acc             (conv3 pre-pool, no bias)
template <int MODE>
__global__ __launch_bounds__(256) void agg_kernel(const ushort* __restrict__ msg,
                                                  const float* __restrict__ dinv,
                                                  const int* __restrict__ ptr,
                                                  const int* __restrict__ cnt,
                                                  const int2* __restrict__ edges,
                                                  const float* __restrict__ bias,
                                                  void* __restrict__ outp) {
  int wave = (blockIdx.x * 256 + threadIdx.x) >> 6;
  int lane = threadIdx.x & 63;
  if (wave >= N_NODES) return;
  int v = wave;
  float di = dinv[v];
  const uint32_t* m32 = (const uint32_t*)msg;   // 64 dwords per node row
  uint32_t su = m32[(size_t)v * 64 + lane];     // self term, weight di
  float ax0 = di * bfLo(su), ay0 = di * bfHi(su);
  float ax1 = 0.f, ay1 = 0.f, ax2 = 0.f, ay2 = 0.f, ax3 = 0.f, ay3 = 0.f;
  int start = ptr[v];
  int n = cnt[v];
  int i = 0;
  if ((start & 1) && n > 0) {                   // align to int4 (2-edge) bound
    int2 e = edges[start];
    uint32_t u = m32[(size_t)e.x * 64 + lane];
    float nrm = __int_as_float(e.y);
    ax0 = fmaf(nrm, bfLo(u), ax0);
    ay0 = fmaf(nrm, bfHi(u), ay0);
    i = 1;
  }
  for (; i + 8 <= n; i += 8) {
    const int4* ep = (const int4*)(edges + start + i);   // 16B-aligned
    int4 q0 = ep[0], q1 = ep[1], q2 = ep[2], q3 = ep[3];
    uint32_t u0 = m32[(size_t)q0.x * 64 + lane];
    uint32_t u1 = m32[(size_t)q0.z * 64 + lane];
    uint32_t u2 = m32[(size_t)q1.x * 64 + lane];
    uint32_t u3 = m32[(size_t)q1.z * 64 + lane];
    uint32_t u4 = m32[(size_t)q2.x * 64 + lane];
    uint32_t u5 = m32[(size_t)q2.z * 64 + lane];
    uint32_t u6 = m32[(size_t)q3.x * 64 + lane];
    uint32_t u7 = m32[(size_t)q3.z * 64 + lane];
    float n0 = __int_as_float(q0.y), n1 = __int_as_float(q0.w);
    float n2 = __int_as_float(q1.y), n3 = __int_as_float(q1.w);
    float n4 = __int_as_float(q2.y), n5 = __int_as_float(q2.w);
    float n6 = __int_as_float(q3.y), n7 = __int_as_float(q3.w);
    ax0 = fmaf(n0, bfLo(u0), ax0); ay0 = fmaf(n0, bfHi(u0), ay0);
    ax1 = fmaf(n1, bfLo(u1), ax1); ay1 = fmaf(n1, bfHi(u1), ay1);
    ax2 = fmaf(n2, bfLo(u2), ax2); ay2 = fmaf(n2, bfHi(u2), ay2);
    ax3 = fmaf(n3, bfLo(u3), ax3); ay3 = fmaf(n3, bfHi(u3), ay3);
    ax0 = fmaf(n4, bfLo(u4), ax0); ay0 = fmaf(n4, bfHi(u4), ay0);
    ax1 = fmaf(n5, bfLo(u5), ax1); ay1 = fmaf(n5, bfHi(u5), ay1);
    ax2 = fmaf(n6, bfLo(u6), ax2); ay2 = fmaf(n6, bfHi(u6), ay2);
    ax3 = fmaf(n7, bfLo(u7), ax3); ay3 = fmaf(n7, bfHi(u7), ay3);
  }
  for (; i < n; ++i) {
    int2 e = edges[start + i];
    float nrm = __int_as_float(e.y);
    uint32_t u = m32[(size_t)e.x * 64 + lane];
    ax0 = fmaf(nrm, bfLo(u), ax0);
    ay0 = fmaf(nrm, bfHi(u), ay0);
  }
  float ax = (ax0 + ax1) + (ax2 + ax3);
  float ay = (ay0 + ay1) + (ay2 + ay3);
  if (MODE == 2) {
    ((float2*)outp)[(size_t)v * 64 + lane] = make_float2(ax * di, ay * di);
  } else {
    ax = fmaf(ax, di, bias[2 * lane]);
    ay = fmaf(ay, di, bias[2 * lane + 1]);
    ax = fmaxf(ax, 0.f);
    ay = fmaxf(ay, 0.f);
    ushort2 h2;
    h2.x = f2bf(ax);
    h2.y = f2bf(ay);
    ((ushort2*)outp)[(size_t)v * 64 + lane] = h2;
  }
}

// ---------------- pool: segment-sum a3 over batch-sorted nodes -----------
__global__ __launch_bounds__(256) void pool_sum(const float* __restrict__ a3,
                                                const int* __restrict__ batch,
                                                float* __restrict__ P) {
  int wave = blockIdx.x * 4 + (threadIdx.x >> 6);
  int lane = threadIdx.x & 63;
  int v0 = wave * 16;
  if (v0 >= N_NODES) return;
  int vend = v0 + 16;
  if (vend > N_NODES) vend = N_NODES;
  const float2* a2 = (const float2*)a3;
  float ax = 0.f, ay = 0.f;
  int g = batch[v0];
  for (int v = v0; v < vend; ++v) {
    int gv = batch[v];
    if (gv != g) {
      atomicAdd(&P[(size_t)g * FEAT + 2 * lane], ax);
      atomicAdd(&P[(size_t)g * FEAT + 2 * lane + 1], ay);
      ax = 0.f; ay = 0.f; g = gv;
    }
    float2 t = a2[(size_t)v * 64 + lane];
    ax += t.x;
    ay += t.y;
  }
  atomicAdd(&P[(size_t)g * FEAT + 2 * lane], ax);
  atomicAdd(&P[(size_t)g * FEAT + 2 * lane + 1], ay);
}

// ---------------- fused head: Pn = P/cnt; f = Pn*W3+b3; fc1..fc5 ---------
__device__ __forceinline__ void head_layer(const float* __restrict__ IN,
                                           float* __restrict__ OUT,
                                           const float* __restrict__ w,
                                           const float* __restrict__ b,
                                           int K, int C, int Cp, int relu,
                                           float* __restrict__ gout, int t) {
  int parts = 1024 / Cp;
  int part = t / Cp;
  int c = t - part * Cp;
  int kchunk = K / parts;
  if (t < C) OUT[t] = b[t];
  __syncthreads();
  if (c < C) {
    int k0 = part * kchunk;
    float a0 = 0.f, a1 = 0.f, a2 = 0.f, a3 = 0.f;
    const float* wp = w + (size_t)k0 * C + c;
    if ((kchunk & 3) == 0) {
#pragma unroll 4
      for (int k = 0; k < kchunk; k += 4) {
        a0 = fmaf(IN[k0 + k],     wp[(size_t)k * C],       a0);
        a1 = fmaf(IN[k0 + k + 1], wp[(size_t)(k + 1) * C], a1);
        a2 = fmaf(IN[k0 + k + 2], wp[(size_t)(k + 2) * C], a2);
        a3 = fmaf(IN[k0 + k + 3], wp[(size_t)(k + 3) * C], a3);
      }
    } else {
      for (int k = 0; k < kchunk; ++k)
        a0 = fmaf(IN[k0 + k], wp[(size_t)k * C], a0);
    }
    atomicAdd(&OUT[c], (a0 + a1) + (a2 + a3));
  }
  __syncthreads();
  if (t < C) {
    float v = OUT[t];
    if (relu) { v = fmaxf(v, 0.f); OUT[t] = v; }
    if (gout) gout[t] = v;
  }
  __syncthreads();
}

__global__ __launch_bounds__(1024) void fc_head(const float* __restrict__ P,
                                                const float* __restrict__ cnt_g,
                                                const float* __restrict__ w3,
                                                const float* __restrict__ b3,
                                                const float* __restrict__ w1,
                                                const float* __restrict__ b1,
                                                const float* __restrict__ w2,
                                                const float* __restrict__ b2,
                                                const float* __restrict__ wf3,
                                                const float* __restrict__ bf3,
                                                const float* __restrict__ w4,
                                                const float* __restrict__ b4,
                                                const float* __restrict__ w5,
                                                const float* __restrict__ b5,
                                                float* __restrict__ out_f,
                                                float* __restrict__ out_y) {
  __shared__ float A[1024];
  __shared__ float B[1024];
  int r = blockIdx.x, t = threadIdx.x;
  if (t < FEAT) A[t] = P[r * FEAT + t] / fmaxf(cnt_g[r], 1.0f);   // Pn
  __syncthreads();
  head_layer(A, B, w3, b3, 128, 128, 128, 0, out_f + (size_t)r * FEAT, t);
  head_layer(B, A, w1, b1, 128, 1024, 1024, 1, nullptr, t);
  head_layer(A, B, w2, b2, 1024, 512, 512, 1, nullptr, t);
  head_layer(B, A, wf3, bf3, 512, 256, 256, 1, nullptr, t);
  head_layer(A, B, w4, b4, 256, 128, 128, 1, nullptr, t);
  head_layer(B, A, w5, b5, 128, 10, 16, 0, out_y + (size_t)r * 10, t);
}

// =========================================================================
extern "C" void kernel_launch(void* const* d_in, const int* in_sizes, int n_in,
                              void* d_out, int out_size, void* d_ws, size_t ws_size,
                              hipStream_t stream) {
  const float* x         = (const float*)d_in[0];
  const int*   ei        = (const int*)d_in[1];     // [2][E]: row0 src, row1 dst
  const int*   batch     = (const int*)d_in[2];
  const float* conv_w[3] = {(const float*)d_in[3], (const float*)d_in[5], (const float*)d_in[7]};
  const float* conv_b[3] = {(const float*)d_in[4], (const float*)d_in[6], (const float*)d_in[8]};
  const float* fc_w[5]   = {(const float*)d_in[9],  (const float*)d_in[11],
                            (const float*)d_in[13], (const float*)d_in[15],
                            (const float*)d_in[17]};
  const float* fc_b[5]   = {(const float*)d_in[10], (const float*)d_in[12],
                            (const float*)d_in[14], (const float*)d_in[16],
                            (const float*)d_in[18]};
  const int* e_src = ei;
  const int* e_dst = ei + N_EDGES;
  float* out_f = (float*)d_out;                  // [64][128] fp32  (output 0)
  float* out_y = (float*)d_out + NGRAPH * FEAT;  // [64][10]  fp32  (output 1)

  char* p = (char*)d_ws;
  auto carve = [&](size_t bytes) {
    char* r = p;
    p += (bytes + 255) & ~(size_t)255;
    return r;
  };
  int*    cnt_i   = (int*)carve(N_NODES * 4);
  float*  dinv    = (float*)carve(N_NODES * 4);
  int*    csr_ptr = (int*)carve(N_NODES * 4);
  int*    bsums   = (int*)carve(256 * 4);
  int2*   edges   = (int2*)carve((size_t)N_EDGES * 8);            // {src, dinv_s}
  ushort* wbT     = (ushort*)carve((size_t)2 * FEAT * FEAT * 2);  // bf16 W^T conv1/2
  ushort* hbuf    = (ushort*)carve((size_t)N_NODES * FEAT * 2);   // bf16 h
  float*  f_sum   = (float*)carve(NGRAPH * FEAT * 4);             // P
  float*  cnt_g   = (float*)carve(NGRAPH * 4);                    // adjacent to f_sum
  // Shared region (25.6 MB): rank (3.2M) + msl (12.8M) live early; a3 (fp32
  // [N][128]) overlays the whole region. rank dead after fill_csr; msl dead
  // after agg<0> (conv2 reuses msl, dead after 2nd agg<0>); a3 written by
  // agg<2> which reads only hbuf/edges/ptr/cnt -> no overlap hazard.
  char*   region  = carve((size_t)N_NODES * FEAT * 4);
  int*    rank    = (int*)region;
  ushort* msl     = (ushort*)(region + (size_t)N_EDGES * 4);
  float*  a3      = (float*)region;

  const int BLK_N = (N_NODES + 255) / 256;   // 196

  // zero-init (ws + out are poisoned 0xAA each timed call)
  hipMemsetAsync(cnt_i, 0, N_NODES * 4, stream);
  hipMemsetAsync(f_sum, 0, NGRAPH * FEAT * 4 + 256, stream);      // f_sum + cnt_g

  // ---- tiny weight transpose-cvt (feeds gemm_rank) ----
  wcvt<<<32, 256, 0, stream>>>(conv_w[0], conv_w[1], wbT);

  // ---- K1: conv1 gemm (fp32 A, in-reg cvt) overlapped with rank atomics --
  gemm_rank<<<GR_BLKS, 256, 0, stream>>>(x, wbT, msl, e_dst, cnt_i, rank);

  // ---- dinv + graph counts + scan1 (1 dispatch) ----
  dinv_scan1<<<BLK_N, 256, 0, stream>>>(cnt_i, batch, dinv, cnt_g, csr_ptr, bsums);
  scan2<<<1, 256, 0, stream>>>(bsums, BLK_N);
  scan3<<<BLK_N, 256, 0, stream>>>(csr_ptr, bsums);

  // ---- atomic-free CSR fill ----
  fill_csr<<<E_BLKS, 256, 0, stream>>>(e_src, e_dst, rank, csr_ptr, dinv, edges);

  const int AGG_BLKS  = (N_NODES + 3) / 4;
  const int POOL_BLKS = (N_NODES / 16 + 3) / 4 + 1;

  // ---- conv1 agg: h1 = relu(di*acc + b1) ----
  agg_kernel<0><<<AGG_BLKS, 256, 0, stream>>>(msl, dinv, csr_ptr, cnt_i, edges,
                                              conv_b[0], hbuf);
  // ---- conv2: msg2 = h1 W2; h2 = relu(di*acc + b2) ----
  gemm128<<<GEMM_BLKS, 256, 0, stream>>>(hbuf, wbT + FEAT * FEAT, msl);
  agg_kernel<0><<<AGG_BLKS, 256, 0, stream>>>(msl, dinv, csr_ptr, cnt_i, edges,
                                              conv_b[1], hbuf);
  // ---- conv3 pre-pool: a3 = di*acc(h2), fp32 ----
  agg_kernel<2><<<AGG_BLKS, 256, 0, stream>>>(hbuf, dinv, csr_ptr, cnt_i, edges,
                                              nullptr, a3);
  // ---- per-graph segment sum (batch sorted) ----
  pool_sum<<<POOL_BLKS, 256, 0, stream>>>(a3, batch, f_sum);

  // ---- fused head: Pn -> W3 -> fc1..fc5 (one launch) ----
  fc_head<<<NGRAPH, 1024, 0, stream>>>(f_sum, cnt_g, conv_w[2], conv_b[2],
                                       fc_w[0], fc_b[0], fc_w[1], fc_b[1],
                                       fc_w[2], fc_b[2], fc_w[3], fc_b[3],
                                       fc_w[4], fc_b[4], out_f, out_y);
}